// Round 1
// baseline (1391.278 us; speedup 1.0000x reference)
//
#include <hip/hip_runtime.h>
#include <cstddef>

// Problem constants (from reference)
constexpr int kB  = 4;
constexpr int kS  = 2048;
constexpr int kH  = 512;
constexpr int kNH = 8;
constexpr int kHD = 64;
constexpr int kM  = kB * kS;        // 8192 rows for the projection GEMMs
constexpr int kK  = 512;            // inner dim for all projection GEMMs

#define FMA16(a, b)                                                        \
  do {                                                                     \
    acc[0][0] += a.x * b.x; acc[0][1] += a.x * b.y;                        \
    acc[0][2] += a.x * b.z; acc[0][3] += a.x * b.w;                        \
    acc[1][0] += a.y * b.x; acc[1][1] += a.y * b.y;                        \
    acc[1][2] += a.y * b.z; acc[1][3] += a.y * b.w;                        \
    acc[2][0] += a.z * b.x; acc[2][1] += a.z * b.y;                        \
    acc[2][2] += a.z * b.z; acc[2][3] += a.z * b.w;                        \
    acc[3][0] += a.w * b.x; acc[3][1] += a.w * b.y;                        \
    acc[3][2] += a.w * b.z; acc[3][3] += a.w * b.w;                        \
  } while (0)

// C = A(M,512) * W(512,512)^T + bias, NT GEMM, 64x64 tile, 4x4 per thread.
// MODE 0: store head-major  out[((b*NH+h)*S + s)*HD + d]   (QKV projections)
// MODE 1: store row-major   out[m*512 + n]                 (output projection)
template <int MODE>
__global__ __launch_bounds__(256) void gemm_nt_bias(
    const float* __restrict__ A, const float* __restrict__ W,
    const float* __restrict__ bias, float* __restrict__ out)
{
  __shared__ __align__(16) float As[16][68];   // [k][m], padded
  __shared__ __align__(16) float Ws[16][68];   // [k][n], padded

  const int tid  = threadIdx.x;
  const int ty   = tid >> 4;          // 0..15
  const int tx   = tid & 15;          // 0..15
  const int m0   = blockIdx.x * 64;
  const int n0   = blockIdx.y * 64;
  const int lrow = tid >> 2;          // 0..63
  const int lcol = (tid & 3) << 2;    // 0,4,8,12

  float acc[4][4] = {};

  for (int k0 = 0; k0 < kK; k0 += 16) {
    float4 av = *(const float4*)(A + (size_t)(m0 + lrow) * kK + k0 + lcol);
    float4 wv = *(const float4*)(W + (size_t)(n0 + lrow) * kK + k0 + lcol);
    __syncthreads();
    As[lcol + 0][lrow] = av.x; As[lcol + 1][lrow] = av.y;
    As[lcol + 2][lrow] = av.z; As[lcol + 3][lrow] = av.w;
    Ws[lcol + 0][lrow] = wv.x; Ws[lcol + 1][lrow] = wv.y;
    Ws[lcol + 2][lrow] = wv.z; Ws[lcol + 3][lrow] = wv.w;
    __syncthreads();
#pragma unroll
    for (int kk = 0; kk < 16; ++kk) {
      float4 a = *(const float4*)&As[kk][ty << 2];
      float4 b = *(const float4*)&Ws[kk][tx << 2];
      FMA16(a, b);
    }
  }

  float4 bv = *(const float4*)(bias + n0 + (tx << 2));
#pragma unroll
  for (int i = 0; i < 4; ++i) {
    const int m = m0 + (ty << 2) + i;
    float4 o = make_float4(acc[i][0] + bv.x, acc[i][1] + bv.y,
                           acc[i][2] + bv.z, acc[i][3] + bv.w);
    if (MODE == 0) {
      const int b = m >> 11;            // m / S
      const int s = m & (kS - 1);
      const int h = n0 >> 6;            // tile is head-aligned (64 = HD)
      const size_t idx =
          (((size_t)(b * kNH + h)) * kS + s) * kHD + (tx << 2);
      *(float4*)(out + idx) = o;
    } else {
      *(float4*)(out + (size_t)m * kH + n0 + (tx << 2)) = o;
    }
  }
}

// scores[bh][i][j] = scale * sum_d Q[bh][i][d] * K[bh][j][d]
// One block: 64x64 output tile, full K-depth (HD=64) in one shot.
__global__ __launch_bounds__(256) void scores_kernel(
    const float* __restrict__ Q, const float* __restrict__ Kh,
    float* __restrict__ attn)
{
  __shared__ __align__(16) float Qs[64][68];   // [d][i]
  __shared__ __align__(16) float Ks[64][68];   // [d][j]

  const int tid = threadIdx.x;
  const int ty  = tid >> 4;
  const int tx  = tid & 15;
  const int i0  = blockIdx.x * 64;
  const int j0  = blockIdx.y * 64;
  const int bh  = blockIdx.z;

  const float* Qb = Q  + (size_t)bh * kS * kHD;
  const float* Kb = Kh + (size_t)bh * kS * kHD;

#pragma unroll
  for (int it = 0; it < 4; ++it) {
    const int t   = tid + it * 256;
    const int row = t >> 4;             // 0..63
    const int c4  = (t & 15) << 2;      // 0..60
    float4 q  = *(const float4*)(Qb + (size_t)(i0 + row) * kHD + c4);
    float4 kv = *(const float4*)(Kb + (size_t)(j0 + row) * kHD + c4);
    Qs[c4 + 0][row] = q.x;  Qs[c4 + 1][row] = q.y;
    Qs[c4 + 2][row] = q.z;  Qs[c4 + 3][row] = q.w;
    Ks[c4 + 0][row] = kv.x; Ks[c4 + 1][row] = kv.y;
    Ks[c4 + 2][row] = kv.z; Ks[c4 + 3][row] = kv.w;
  }
  __syncthreads();

  float acc[4][4] = {};
#pragma unroll 8
  for (int kk = 0; kk < 64; ++kk) {
    float4 a = *(const float4*)&Qs[kk][ty << 2];
    float4 b = *(const float4*)&Ks[kk][tx << 2];
    FMA16(a, b);
  }

  const float scale = 0.125f;           // HD^-0.5
#pragma unroll
  for (int i = 0; i < 4; ++i) {
    const size_t ridx =
        ((size_t)bh * kS + i0 + (ty << 2) + i) * kS + j0 + (tx << 2);
    *(float4*)(attn + ridx) = make_float4(acc[i][0] * scale, acc[i][1] * scale,
                                          acc[i][2] * scale, acc[i][3] * scale);
  }
}

// In-place row softmax over rows of length S=2048. One block per row.
__global__ __launch_bounds__(256) void softmax_kernel(float* __restrict__ attn)
{
  float* p = attn + (size_t)blockIdx.x * kS;
  const int tid = threadIdx.x;

  float4 v0 = ((const float4*)p)[tid];
  float4 v1 = ((const float4*)p)[tid + 256];

  float m = fmaxf(fmaxf(fmaxf(v0.x, v0.y), fmaxf(v0.z, v0.w)),
                  fmaxf(fmaxf(v1.x, v1.y), fmaxf(v1.z, v1.w)));
#pragma unroll
  for (int o = 32; o > 0; o >>= 1) m = fmaxf(m, __shfl_xor(m, o));

  __shared__ float redm[4];
  __shared__ float reds[4];
  const int w = tid >> 6;
  if ((tid & 63) == 0) redm[w] = m;
  __syncthreads();
  m = fmaxf(fmaxf(redm[0], redm[1]), fmaxf(redm[2], redm[3]));

  v0.x = __expf(v0.x - m); v0.y = __expf(v0.y - m);
  v0.z = __expf(v0.z - m); v0.w = __expf(v0.w - m);
  v1.x = __expf(v1.x - m); v1.y = __expf(v1.y - m);
  v1.z = __expf(v1.z - m); v1.w = __expf(v1.w - m);

  float s = v0.x + v0.y + v0.z + v0.w + v1.x + v1.y + v1.z + v1.w;
#pragma unroll
  for (int o = 32; o > 0; o >>= 1) s += __shfl_xor(s, o);
  if ((tid & 63) == 0) reds[w] = s;
  __syncthreads();
  s = reds[0] + reds[1] + reds[2] + reds[3];

  const float inv = 1.0f / s;
  v0.x *= inv; v0.y *= inv; v0.z *= inv; v0.w *= inv;
  v1.x *= inv; v1.y *= inv; v1.z *= inv; v1.w *= inv;
  ((float4*)p)[tid] = v0;
  ((float4*)p)[tid + 256] = v1;
}

// ctx[b][s][h*HD+d] = sum_k P[bh][s][k] * V[bh][k][d]
// One block: 64 rows (s) x 64 cols (d = full head), K-loop over S in 64 chunks.
__global__ __launch_bounds__(256) void pv_kernel(
    const float* __restrict__ attn, const float* __restrict__ V,
    float* __restrict__ ctx)
{
  __shared__ __align__(16) float Ps[64][68];   // [k][i]
  __shared__ __align__(16) float Vs[64][68];   // [k][d]

  const int tid = threadIdx.x;
  const int ty  = tid >> 4;
  const int tx  = tid & 15;
  const int i0  = blockIdx.x * 64;
  const int bh  = blockIdx.y;
  const int b   = bh >> 3;
  const int h   = bh & 7;

  const float* Pb = attn + ((size_t)bh * kS + i0) * kS;
  const float* Vb = V + (size_t)bh * kS * kHD;

  float acc[4][4] = {};
  for (int k0 = 0; k0 < kS; k0 += 64) {
    __syncthreads();
#pragma unroll
    for (int it = 0; it < 4; ++it) {
      const int t   = tid + it * 256;
      const int row = t >> 4;
      const int c4  = (t & 15) << 2;
      float4 pv = *(const float4*)(Pb + (size_t)row * kS + k0 + c4);
      float4 vv = *(const float4*)(Vb + (size_t)(k0 + row) * kHD + c4);
      Ps[c4 + 0][row] = pv.x; Ps[c4 + 1][row] = pv.y;
      Ps[c4 + 2][row] = pv.z; Ps[c4 + 3][row] = pv.w;
      *(float4*)&Vs[row][c4] = vv;
    }
    __syncthreads();
#pragma unroll 8
    for (int kk = 0; kk < 64; ++kk) {
      float4 a = *(const float4*)&Ps[kk][ty << 2];
      float4 b = *(const float4*)&Vs[kk][tx << 2];
      FMA16(a, b);
    }
  }

#pragma unroll
  for (int i = 0; i < 4; ++i) {
    const int s = i0 + (ty << 2) + i;
    const size_t idx = ((size_t)b * kS + s) * kH + h * kHD + (tx << 2);
    *(float4*)(ctx + idx) =
        make_float4(acc[i][0], acc[i][1], acc[i][2], acc[i][3]);
  }
}

extern "C" void kernel_launch(void* const* d_in, const int* in_sizes, int n_in,
                              void* d_out, int out_size, void* d_ws,
                              size_t ws_size, hipStream_t stream)
{
  (void)in_sizes; (void)n_in; (void)out_size;

  const float* query  = (const float*)d_in[0];
  const float* key_in = (const float*)d_in[1];
  const float* value  = (const float*)d_in[2];
  const float* Wq = (const float*)d_in[3];
  const float* bq = (const float*)d_in[4];
  const float* Wk = (const float*)d_in[5];
  const float* bk = (const float*)d_in[6];
  const float* Wv = (const float*)d_in[7];
  const float* bv = (const float*)d_in[8];
  const float* Wo = (const float*)d_in[9];
  const float* bo = (const float*)d_in[10];

  float* out  = (float*)d_out;
  float* attn = out + (size_t)kB * kS * kH;   // attention region of d_out

  const size_t headElems = (size_t)kB * kNH * kS * kHD;   // 4,194,304
  if (ws_size < 4 * headElems * sizeof(float)) return;    // loud failure if ws too small

  float* Qh  = (float*)d_ws;
  float* Kh  = Qh + headElems;
  float* Vh  = Kh + headElems;
  float* ctx = Vh + headElems;

  const dim3 blk(256);
  const dim3 gproj(kM / 64, kH / 64);          // 128 x 8
  gemm_nt_bias<0><<<gproj, blk, 0, stream>>>(query,  Wq, bq, Qh);
  gemm_nt_bias<0><<<gproj, blk, 0, stream>>>(key_in, Wk, bk, Kh);
  gemm_nt_bias<0><<<gproj, blk, 0, stream>>>(value,  Wv, bv, Vh);

  const dim3 gsc(kS / 64, kS / 64, kB * kNH);  // 32 x 32 x 32
  scores_kernel<<<gsc, blk, 0, stream>>>(Qh, Kh, attn);

  softmax_kernel<<<dim3(kB * kNH * kS), blk, 0, stream>>>(attn);

  const dim3 gpv(kS / 64, kB * kNH);           // 32 x 32
  pv_kernel<<<gpv, blk, 0, stream>>>(attn, Vh, ctx);

  gemm_nt_bias<1><<<gproj, blk, 0, stream>>>(ctx, Wo, bo, out);
}